// Round 1
// baseline (375.654 us; speedup 1.0000x reference)
//
#include <hip/hip_runtime.h>

#define HH 1024
#define WW 1024
#define TS 32
#define HALO 6
#define UT (TS + 2*HALO)   // 44
#define LT (TS + 8)        // 40
#define GT (TS + 4)        // 36
#define DTC (0.1f/3.0f)

__global__ __launch_bounds__(256) void pde_layer(
    const float* __restrict__ Uin,
    const float* __restrict__ K1,
    const float* __restrict__ K2,
    const float* __restrict__ Aw,
    float* __restrict__ Uout)
{
    __shared__ float sU[UT][UT + 1];
    __shared__ float sL0[LT][LT + 1];
    __shared__ float sL1[LT][LT + 1];
    __shared__ float sG[GT][GT + 1];

    const int tid = threadIdx.x;
    const int bx = blockIdx.x * TS;
    const int by = blockIdx.y * TS;
    const size_t plane = (size_t)blockIdx.z * (size_t)(HH * WW);
    const float* __restrict__ Ub = Uin + plane;
    float* __restrict__ Ob = Uout + plane;

    // ---- stage 0: load U tile with circular wrap ----
    for (int idx = tid; idx < UT * UT; idx += 256) {
        int r = idx / UT;
        int c = idx - r * UT;
        int gr = (by + r - HALO) & (HH - 1);
        int gc = (bx + c - HALO) & (WW - 1);
        sU[r][c] = Ub[gr * WW + gc];
    }

    // uniform weight loads (scalar)
    float w0[25], w1[25];
    #pragma unroll
    for (int t = 0; t < 25; ++t) { w0[t] = K1[t]; w1[t] = K1[25 + t]; }
    const float k2a = K2[0], k2b = K2[1];

    __syncthreads();

    // ---- stage 1: lam[ch] = relu(conv5x5(U)) * K2[ch] on 40x40 ----
    // lam global row (by-4+r) needs sU rows r..r+4
    for (int it = tid; it < LT * (LT / 4); it += 256) {
        int c  = it % LT;
        int r0 = (it / LT) * 4;
        float a0[4] = {0.f,0.f,0.f,0.f};
        float a1[4] = {0.f,0.f,0.f,0.f};
        #pragma unroll
        for (int ri = 0; ri < 8; ++ri) {
            float u[5];
            #pragma unroll
            for (int j = 0; j < 5; ++j) u[j] = sU[r0 + ri][c + j];
            #pragma unroll
            for (int k = 0; k < 4; ++k) {
                const int i = ri - k;
                if (i >= 0 && i < 5) {
                    #pragma unroll
                    for (int j = 0; j < 5; ++j) {
                        a0[k] = fmaf(u[j], w0[i*5 + j], a0[k]);
                        a1[k] = fmaf(u[j], w1[i*5 + j], a1[k]);
                    }
                }
            }
        }
        #pragma unroll
        for (int k = 0; k < 4; ++k) {
            sL0[r0 + k][c] = fmaxf(a0[k], 0.f) * k2a;
            sL1[r0 + k][c] = fmaxf(a1[k], 0.f) * k2b;
        }
    }
    __syncthreads();

    // ---- stage 2: grad = conv5x5(lam, flipped K1, summed over ch) on 36x36 ----
    // weight for tap (i,j) is K1[ch][4-i][4-j] => index 24 - (i*5+j)
    for (int it = tid; it < GT * (GT / 4); it += 256) {
        int c  = it % GT;
        int r0 = (it / GT) * 4;
        float a[4] = {0.f,0.f,0.f,0.f};
        #pragma unroll
        for (int ri = 0; ri < 8; ++ri) {
            float u0[5], u1[5];
            #pragma unroll
            for (int j = 0; j < 5; ++j) {
                u0[j] = sL0[r0 + ri][c + j];
                u1[j] = sL1[r0 + ri][c + j];
            }
            #pragma unroll
            for (int k = 0; k < 4; ++k) {
                const int i = ri - k;
                if (i >= 0 && i < 5) {
                    #pragma unroll
                    for (int j = 0; j < 5; ++j) {
                        a[k] = fmaf(u0[j], w0[24 - (i*5 + j)], a[k]);
                        a[k] = fmaf(u1[j], w1[24 - (i*5 + j)], a[k]);
                    }
                }
            }
        }
        #pragma unroll
        for (int k = 0; k < 4; ++k) sG[r0 + k][c] = a[k];
    }

    // A weights (only needed in stage 3)
    float aw[25];
    #pragma unroll
    for (int t = 0; t < 25; ++t) aw[t] = Aw[t];

    __syncthreads();

    // ---- stage 3: vec = conv5x5(grad, A); U_out = U + dt/3 * vec on 32x32 ----
    {
        int c  = tid & (TS - 1);
        int r0 = (tid >> 5) * 4;
        float a[4] = {0.f,0.f,0.f,0.f};
        #pragma unroll
        for (int ri = 0; ri < 8; ++ri) {
            float u[5];
            #pragma unroll
            for (int j = 0; j < 5; ++j) u[j] = sG[r0 + ri][c + j];
            #pragma unroll
            for (int k = 0; k < 4; ++k) {
                const int i = ri - k;
                if (i >= 0 && i < 5) {
                    #pragma unroll
                    for (int j = 0; j < 5; ++j)
                        a[k] = fmaf(u[j], aw[i*5 + j], a[k]);
                }
            }
        }
        #pragma unroll
        for (int k = 0; k < 4; ++k) {
            int r = r0 + k;
            Ob[(size_t)(by + r) * WW + (bx + c)] =
                sU[r + HALO][c + HALO] + DTC * a[k];
        }
    }
}

extern "C" void kernel_launch(void* const* d_in, const int* in_sizes, int n_in,
                              void* d_out, int out_size, void* d_ws, size_t ws_size,
                              hipStream_t stream) {
    const float* U  = (const float*)d_in[0];
    const float* K1 = (const float*)d_in[1];
    const float* K2 = (const float*)d_in[2];
    const float* Aw = (const float*)d_in[3];
    float* out = (float*)d_out;
    float* ws  = (float*)d_ws;

    const int B = in_sizes[0] / (HH * WW);   // 16
    dim3 grid(WW / TS, HH / TS, B);

    // 3 Euler layers; grid-wide dependency handled by separate launches.
    // Ping-pong: in -> out -> ws -> out  (needs only one 64MB scratch buffer)
    pde_layer<<<grid, 256, 0, stream>>>(U,   K1, K2, Aw, out);
    pde_layer<<<grid, 256, 0, stream>>>(out, K1, K2, Aw, ws);
    pde_layer<<<grid, 256, 0, stream>>>(ws,  K1, K2, Aw, out);
}

// Round 2
// 279.257 us; speedup vs baseline: 1.3452x; 1.3452x over previous
//
#include <hip/hip_runtime.h>

#define HH 1024
#define WW 1024
#define TW 64
#define TH 32
#define SUS 76   // sU stride (floats), 44 rows, origin col = bx-6
#define SLS 72   // sL stride, 40 rows, origin col = bx-4
#define SGS 68   // sG stride, 36 rows, origin col = bx-2
#define DTC (0.1f/3.0f)

__global__ __launch_bounds__(256) void pde_layer(
    const float* __restrict__ Uin,
    const float* __restrict__ K1,
    const float* __restrict__ K2,
    const float* __restrict__ Aw,
    float* __restrict__ Uout)
{
    // sG (36x68=9792B) overlays sU (44x76=13376B); identity term re-read from global
    __shared__ __align__(16) float sUG[44 * SUS];
    __shared__ __align__(16) float sL0[40 * SLS];
    __shared__ __align__(16) float sL1[40 * SLS];
    float* const sU = sUG;
    float* const sG = sUG;

    const int tid = threadIdx.x;
    const int bx = blockIdx.x * TW;
    const int by = blockIdx.y * TH;
    const size_t plane = (size_t)blockIdx.z * (size_t)(HH * WW);
    const float* __restrict__ Ub = Uin + plane;
    float* __restrict__ Ob = Uout + plane;

    // uniform weights -> SGPRs
    float w0[25], w1[25], aw[25];
    #pragma unroll
    for (int t = 0; t < 25; ++t) { w0[t] = K1[t]; w1[t] = K1[25 + t]; aw[t] = Aw[t]; }
    const float k2a = K2[0], k2b = K2[1];

    // ---- stage 0: load U tile 44 rows x 76 cols (circular wrap), b128 LDS writes ----
    for (int it = tid; it < 44 * 19; it += 256) {
        int r  = it / 19;
        int q  = it - r * 19;
        int gr = (by + r - 6) & (HH - 1);
        int c0 = q * 4;
        const float* row = Ub + (size_t)gr * WW;
        float4 v;
        v.x = row[(bx + c0 - 6 + 0) & (WW - 1)];
        v.y = row[(bx + c0 - 6 + 1) & (WW - 1)];
        v.z = row[(bx + c0 - 6 + 2) & (WW - 1)];
        v.w = row[(bx + c0 - 6 + 3) & (WW - 1)];
        *(float4*)&sU[r * SUS + c0] = v;
    }
    __syncthreads();

    // ---- stage 1: lam[ch] = relu(conv5(U,K1ch))*K2ch on 40r x 72c, 4x4 blocking ----
    if (tid < 180) {
        const int rg = tid / 18;
        const int cg = tid - rg * 18;
        const float* src = &sU[(rg * 4) * SUS + cg * 4];
        float acc0[4][4] = {}, acc1[4][4] = {};
        #pragma unroll
        for (int ri = 0; ri < 8; ++ri) {
            float u[8];
            *(float4*)&u[0] = *(const float4*)&src[ri * SUS];
            *(float4*)&u[4] = *(const float4*)&src[ri * SUS + 4];
            #pragma unroll
            for (int k = 0; k < 4; ++k) {
                const int i = ri - k;
                if (i >= 0 && i < 5) {
                    #pragma unroll
                    for (int j = 0; j < 5; ++j) {
                        const float a = w0[i * 5 + j];
                        const float b = w1[i * 5 + j];
                        #pragma unroll
                        for (int cq = 0; cq < 4; ++cq) {
                            acc0[k][cq] = fmaf(u[cq + j], a, acc0[k][cq]);
                            acc1[k][cq] = fmaf(u[cq + j], b, acc1[k][cq]);
                        }
                    }
                }
            }
        }
        #pragma unroll
        for (int k = 0; k < 4; ++k) {
            float4 o0, o1;
            o0.x = fmaxf(acc0[k][0], 0.f) * k2a;  o1.x = fmaxf(acc1[k][0], 0.f) * k2b;
            o0.y = fmaxf(acc0[k][1], 0.f) * k2a;  o1.y = fmaxf(acc1[k][1], 0.f) * k2b;
            o0.z = fmaxf(acc0[k][2], 0.f) * k2a;  o1.z = fmaxf(acc1[k][2], 0.f) * k2b;
            o0.w = fmaxf(acc0[k][3], 0.f) * k2a;  o1.w = fmaxf(acc1[k][3], 0.f) * k2b;
            *(float4*)&sL0[(rg * 4 + k) * SLS + cg * 4] = o0;
            *(float4*)&sL1[(rg * 4 + k) * SLS + cg * 4] = o1;
        }
    }
    __syncthreads();

    // ---- stage 2: grad = sum_ch conv5(lam_ch, flip(K1ch)) on 36r x 68c ----
    if (tid < 153) {
        const int rg = tid / 17;
        const int cg = tid - rg * 17;
        const float* p0 = &sL0[(rg * 4) * SLS + cg * 4];
        const float* p1 = &sL1[(rg * 4) * SLS + cg * 4];
        float acc[4][4] = {};
        #pragma unroll
        for (int ri = 0; ri < 8; ++ri) {
            float u0[8], u1[8];
            *(float4*)&u0[0] = *(const float4*)&p0[ri * SLS];
            *(float4*)&u0[4] = *(const float4*)&p0[ri * SLS + 4];
            *(float4*)&u1[0] = *(const float4*)&p1[ri * SLS];
            *(float4*)&u1[4] = *(const float4*)&p1[ri * SLS + 4];
            #pragma unroll
            for (int k = 0; k < 4; ++k) {
                const int i = ri - k;
                if (i >= 0 && i < 5) {
                    #pragma unroll
                    for (int j = 0; j < 5; ++j) {
                        const float a = w0[24 - (i * 5 + j)];   // flipped
                        const float b = w1[24 - (i * 5 + j)];
                        #pragma unroll
                        for (int cq = 0; cq < 4; ++cq) {
                            acc[k][cq] = fmaf(u0[cq + j], a, acc[k][cq]);
                            acc[k][cq] = fmaf(u1[cq + j], b, acc[k][cq]);
                        }
                    }
                }
            }
        }
        #pragma unroll
        for (int k = 0; k < 4; ++k) {
            float4 o;
            o.x = acc[k][0]; o.y = acc[k][1]; o.z = acc[k][2]; o.w = acc[k][3];
            *(float4*)&sG[(rg * 4 + k) * SGS + cg * 4] = o;   // overlays sU (done with it)
        }
    }
    __syncthreads();

    // ---- stage 3: out = U + dt/3 * conv5(grad, A) on 32r x 64c ----
    if (tid < 128) {
        const int rg = tid >> 4;
        const int cg = tid & 15;
        const float* p = &sG[(rg * 4) * SGS + cg * 4];
        float acc[4][4] = {};
        #pragma unroll
        for (int ri = 0; ri < 8; ++ri) {
            float u[8];
            *(float4*)&u[0] = *(const float4*)&p[ri * SGS];
            *(float4*)&u[4] = *(const float4*)&p[ri * SGS + 4];
            #pragma unroll
            for (int k = 0; k < 4; ++k) {
                const int i = ri - k;
                if (i >= 0 && i < 5) {
                    #pragma unroll
                    for (int j = 0; j < 5; ++j) {
                        const float a = aw[i * 5 + j];
                        #pragma unroll
                        for (int cq = 0; cq < 4; ++cq)
                            acc[k][cq] = fmaf(u[cq + j], a, acc[k][cq]);
                    }
                }
            }
        }
        #pragma unroll
        for (int k = 0; k < 4; ++k) {
            const int gy = by + rg * 4 + k;
            const int gx = bx + cg * 4;
            float4 id = *(const float4*)&Ub[(size_t)gy * WW + gx];  // identity (aligned, no wrap)
            float4 o;
            o.x = id.x + DTC * acc[k][0];
            o.y = id.y + DTC * acc[k][1];
            o.z = id.z + DTC * acc[k][2];
            o.w = id.w + DTC * acc[k][3];
            *(float4*)&Ob[(size_t)gy * WW + gx] = o;
        }
    }
}

extern "C" void kernel_launch(void* const* d_in, const int* in_sizes, int n_in,
                              void* d_out, int out_size, void* d_ws, size_t ws_size,
                              hipStream_t stream) {
    const float* U  = (const float*)d_in[0];
    const float* K1 = (const float*)d_in[1];
    const float* K2 = (const float*)d_in[2];
    const float* Aw = (const float*)d_in[3];
    float* out = (float*)d_out;
    float* ws  = (float*)d_ws;

    const int B = in_sizes[0] / (HH * WW);   // 16
    dim3 grid(WW / TW, HH / TH, B);

    // 3 Euler layers; ping-pong in -> out -> ws -> out
    pde_layer<<<grid, 256, 0, stream>>>(U,   K1, K2, Aw, out);
    pde_layer<<<grid, 256, 0, stream>>>(out, K1, K2, Aw, ws);
    pde_layer<<<grid, 256, 0, stream>>>(ws,  K1, K2, Aw, out);
}